// Round 5
// baseline (245.854 us; speedup 1.0000x reference)
//
#include <hip/hip_runtime.h>
#include <hip/hip_bf16.h>

#define N_BOXES 8192
#define NW 128            // number of 64-box chunks / 64-bit words per row
#define FEAT 10
#define CMAX 56           // speculative candidate slots (7 worker waves x 8)
#define CJG 8             // cj columns per mask block

typedef unsigned long long u64;
typedef unsigned int u32;

__device__ __forceinline__ void barrier_nodrain() {
    asm volatile("s_waitcnt lgkmcnt(0)" ::: "memory");
    __builtin_amdgcn_sched_barrier(0);
    __builtin_amdgcn_s_barrier();
    __builtin_amdgcn_sched_barrier(0);
    asm volatile("" ::: "memory");
}

// ---------------- Phase A: rank + scatter sorted boxes ----------------
// Descending-score order, ties broken by larger original index first
// (matches jnp.argsort(stable)[::-1]).
__global__ void rank_scatter_kernel(const float* __restrict__ bboxes,
                                    const float* __restrict__ scores,
                                    float* __restrict__ x1s, float* __restrict__ y1s,
                                    float* __restrict__ x2s, float* __restrict__ y2s,
                                    u32* __restrict__ rank_of) {
    __shared__ float sc[N_BOXES];
    int tid = threadIdx.x;
    for (int t = 0; t < N_BOXES / 256; ++t)
        sc[tid + 256 * t] = scores[tid + 256 * t];
    __syncthreads();
    int k = tid >> 3;          // box slot 0..31
    int s = tid & 7;           // segment 0..7
    int i = blockIdx.x * 32 + k;
    float si = sc[i];
    int cnt = 0;
    const float4* sc4 = (const float4*)sc;
    int q0 = s * (N_BOXES / 32);
    #pragma unroll 4
    for (int q = q0; q < q0 + N_BOXES / 32; ++q) {
        float4 v = sc4[q];
        int j = 4 * q;
        cnt += (int)((v.x > si) || (v.x == si && j     > i));
        cnt += (int)((v.y > si) || (v.y == si && j + 1 > i));
        cnt += (int)((v.z > si) || (v.z == si && j + 2 > i));
        cnt += (int)((v.w > si) || (v.w == si && j + 3 > i));
    }
    cnt += __shfl_down(cnt, 4, 8);
    cnt += __shfl_down(cnt, 2, 8);
    cnt += __shfl_down(cnt, 1, 8);
    if (s == 0) {
        int r = cnt;
        float x = bboxes[4 * i + 0], y = bboxes[4 * i + 1];
        float w = bboxes[4 * i + 2], h = bboxes[4 * i + 3];
        float x2 = x + w, y2 = y + h;           // exact ref op order
        x1s[r] = x; y1s[r] = y; x2s[r] = x2; y2s[r] = y2;
        rank_of[i] = (u32)r;
    }
}

// ---------------- Phase B: suppression bitmask matrix ----------------
// Row-major: RM[i*NW + cj] = word over j in chunk cj of sup(i->j) (j>i).
// TRb[d*N + j] (d=0,1) = word over i in chunk (chunk(j)-d) of sup(i->j).
// Block = (8-cj group, ci); 4 waves x 2 cj each; 64x8 u64 tile in LDS,
// stored coalesced (64B contiguous per row).
__global__ void __launch_bounds__(256) mask_kernel(
        const float* __restrict__ x1s, const float* __restrict__ y1s,
        const float* __restrict__ x2s, const float* __restrict__ y2s,
        u64* __restrict__ RM, u64* __restrict__ TRb) {
    int ci = blockIdx.y;
    int cjg0 = blockIdx.x * CJG;
    if (cjg0 + CJG - 1 < ci) return;     // whole group below diagonal
    __shared__ u64 T[64][CJG];           // 4 KiB tile
    __shared__ float SB[4][4][64];       // per-wave staging of looped chunk
    int wv = threadIdx.x >> 6, lane = threadIdx.x & 63;
    int ig0 = ci * 64;
    // per-lane i-chunk box data (row = lane)
    float ix1 = x1s[ig0 + lane], iy1 = y1s[ig0 + lane];
    float ix2 = x2s[ig0 + lane], iy2 = y2s[ig0 + lane];
    float iar = (ix2 - ix1) * (iy2 - iy1);    // bit-identical to ref area
    #pragma unroll
    for (int t = 0; t < 2; ++t) {
        int cjrel = wv * 2 + t;
        int cj = cjg0 + cjrel;
        if (cj < ci) { T[lane][cjrel] = 0; continue; }
        int jg0 = cj * 64;
        int d = cj - ci;
        if (d <= 1) {
            // ballot path: lanes = columns j; i-chunk staged in LDS
            SB[wv][0][lane] = ix1; SB[wv][1][lane] = iy1;
            SB[wv][2][lane] = ix2; SB[wv][3][lane] = iy2;
            int jg = jg0 + lane;
            float jx1 = x1s[jg], jy1 = y1s[jg], jx2 = x2s[jg], jy2 = y2s[jg];
            float jar = (jx2 - jx1) * (jy2 - jy1);
            u64 my = 0, cw = 0;
            for (int ip = 0; ip < 64; ++ip) {
                float ax1 = SB[wv][0][ip], ay1 = SB[wv][1][ip];
                float ax2 = SB[wv][2][ip], ay2 = SB[wv][3][ip];
                float aar = (ax2 - ax1) * (ay2 - ay1);
                float xx1 = fmaxf(ax1, jx1);
                float yy1 = fmaxf(ay1, jy1);
                float xx2 = fminf(ax2, jx2);
                float yy2 = fminf(ay2, jy2);
                float iw = fmaxf(xx2 - xx1, 0.0f);
                float ih = fmaxf(yy2 - yy1, 0.0f);
                float inter = iw * ih;
                float uni = aar + jar - inter;
                float iou = __fdiv_rn(inter, uni);   // IEEE-exact like numpy
                bool sup = (iou > 0.5f) && (jg > ig0 + ip);
                u64 w = __ballot(sup);
                if (lane == ip) my = w;
                cw |= sup ? (1ull << ip) : 0ull;
            }
            T[lane][cjrel] = my;
            TRb[(size_t)d * N_BOXES + jg] = cw;
        } else {
            // direct path: lanes = rows i; j-chunk staged in LDS
            SB[wv][0][lane] = x1s[jg0 + lane];
            SB[wv][1][lane] = y1s[jg0 + lane];
            SB[wv][2][lane] = x2s[jg0 + lane];
            SB[wv][3][lane] = y2s[jg0 + lane];
            u64 my = 0;
            for (int jp = 0; jp < 64; ++jp) {
                float jx1 = SB[wv][0][jp], jy1 = SB[wv][1][jp];
                float jx2 = SB[wv][2][jp], jy2 = SB[wv][3][jp];
                float jar = (jx2 - jx1) * (jy2 - jy1);
                float xx1 = fmaxf(ix1, jx1);
                float yy1 = fmaxf(iy1, jy1);
                float xx2 = fminf(ix2, jx2);
                float yy2 = fminf(iy2, jy2);
                float iw = fmaxf(xx2 - xx1, 0.0f);
                float ih = fmaxf(yy2 - yy1, 0.0f);
                float inter = iw * ih;
                float uni = iar + jar - inter;
                float iou = __fdiv_rn(inter, uni);
                bool sup = (iou > 0.5f);             // cj>ci+1 => j>i always
                my |= sup ? (1ull << jp) : 0ull;
            }
            T[lane][cjrel] = my;
        }
    }
    __syncthreads();
    // coalesced tile store: 16B per thread, 64B contiguous per row
    int row = threadIdx.x >> 2, p = threadIdx.x & 3;
    ulonglong2 v;
    v.x = T[row][2 * p];
    v.y = T[row][2 * p + 1];
    *(ulonglong2*)&RM[(size_t)(ig0 + row) * NW + cjg0 + 2 * p] = v;
}

// ---------------- Phase C+D: greedy reduce (1 block) + fused output ---------
// Per region c (one barrier): wave0 = ballot-fixpoint for chunk c (TR planes
// in LDS; d=1 fold covers chunk c-1). Waves 1-7: COMMIT chunk c-1's kept rows
// (speculatively loaded last region, filtered by final keptw) via full-row
// LDS atomicOr (past-word writes benign), then ISSUE speculative row loads
// for chunk c's candidate list (superset published by wave1 last region).
// Single H buffer: commit-before-issue. CMAX=56 => overflow path is rare.
__global__ void __launch_bounds__(512) nms_reduce_fused(
        const u64* __restrict__ RM, const u64* __restrict__ TRb,
        const u32* __restrict__ rank_of,
        const float* __restrict__ bboxes, const float* __restrict__ features,
        const float* __restrict__ Wm, const float* __restrict__ bv,
        const int* __restrict__ widthp, const int* __restrict__ heightp,
        float* __restrict__ out) {
    __shared__ u64 TR0L[N_BOXES];      // 64 KiB: diag suppressors
    __shared__ u64 TR1L[N_BOXES];      // 64 KiB: prev-chunk suppressors
    __shared__ u32 rem32[NW * 2];
    __shared__ u64 keptw[NW];
    __shared__ __align__(8) unsigned char clist[2][64];
    __shared__ u32 ccnt[2];
    __shared__ u64 ovmsk[2];

    const int tid = threadIdx.x;
    const int wv = tid >> 6, lane = tid & 63;

    #pragma unroll
    for (int k = 0; k < 16; ++k) {
        int idx = tid + 512 * k;
        TR0L[idx] = TRb[idx];
        TR1L[idx] = TRb[N_BOXES + idx];
    }
    if (tid < NW * 2) rem32[tid] = 0;
    if (wv == 1 && lane < CMAX) clist[0][lane] = (unsigned char)lane;
    if (tid == 300) { ccnt[0] = 64; ovmsk[0] = 0xFF00000000000000ull; }
    __syncthreads();

    u64 k_prev = 0;
    u64 H0[8], H1[8];
    #pragma unroll
    for (int s = 0; s < 8; ++s) { H0[s] = 0; H1[s] = 0; }
    u64 Pb = 0, Pov = 0; u32 Pnc = 0;

    for (int c = 0; c < NW; ++c) {
        if (wv == 0) {
            u64 td  = TR0L[c * 64 + lane];
            u64 tf1 = TR1L[c * 64 + lane];
            u64 base = ((u64)rem32[2 * c + 1] << 32) | (u64)rem32[2 * c];
            u64 R = base | __ballot((tf1 & k_prev) != 0ull);
            u64 K = 0, U = ~R;
            bool meU = (U >> lane) & 1;
            while (U) {
                u64 UK = U | K;
                u64 nK = __ballot(meU && ((td & UK) == 0ull));
                K |= nK;
                u64 nR = __ballot(meU && ((td & K) != 0ull));
                U &= ~(K | nR);
                meU = (U >> lane) & 1;
            }
            if (lane == 0) keptw[c] = K;
            k_prev = K;
        } else {
            if (wv == 1 && c + 1 < NW) {
                int cn = c + 1;
                u64 alive = ~(((u64)rem32[2 * cn + 1] << 32) | (u64)rem32[2 * cn]);
                int rk = __popcll(alive & ((1ull << lane) - 1ull));
                bool al = (alive >> lane) & 1;
                if (al && rk < CMAX) clist[cn & 1][rk] = (unsigned char)lane;
                u64 ovm = __ballot(al && rk >= CMAX);
                if (lane == 0) { ccnt[cn & 1] = (u32)__popcll(alive);
                                 ovmsk[cn & 1] = ovm; }
            }
            // COMMIT chunk c-1's kept rows (loaded last region, filter by keptw)
            if (c > 0) {
                u64 Kp = keptw[c - 1];
                u64 s0 = 0, s1 = 0;
                #pragma unroll
                for (int s = 0; s < 8; ++s) {
                    int r = (wv - 1) * 8 + s;
                    int b = (int)((Pb >> (8 * s)) & 0xffu);
                    bool take = (r < (int)Pnc) && ((Kp >> b) & 1ull);
                    s0 |= take ? H0[s] : 0ull;
                    s1 |= take ? H1[s] : 0ull;
                }
                if (s0) { atomicOr(&rem32[2 * lane],     (u32)s0);
                          atomicOr(&rem32[2 * lane + 1], (u32)(s0 >> 32)); }
                if (s1) { atomicOr(&rem32[2 * (64 + lane)],     (u32)s1);
                          atomicOr(&rem32[2 * (64 + lane) + 1], (u32)(s1 >> 32)); }
                u64 ovk = Pov & Kp;
                if (ovk) {           // rare: candidates ranked >= CMAX
                    u64 mm = ovk;
                    int skip = wv - 1;
                    for (int z = 0; z < skip; ++z) mm &= mm - 1;
                    while (mm) {
                        int b = __builtin_ctzll(mm);
                        const u64* rp = RM + ((size_t)(c - 1) * 64 + b) * NW;
                        u64 r0 = rp[lane], r1 = rp[64 + lane];
                        if (r0) { atomicOr(&rem32[2 * lane],     (u32)r0);
                                  atomicOr(&rem32[2 * lane + 1], (u32)(r0 >> 32)); }
                        if (r1) { atomicOr(&rem32[2 * (64 + lane)],     (u32)r1);
                                  atomicOr(&rem32[2 * (64 + lane) + 1], (u32)(r1 >> 32)); }
                        mm &= mm - 1; mm &= mm - 1; mm &= mm - 1; mm &= mm - 1;
                        mm &= mm - 1; mm &= mm - 1; mm &= mm - 1;
                    }
                }
            }
            // ISSUE speculative rows for chunk c (consumed next region)
            if (c != NW - 1) {
                Pnc = ccnt[c & 1];
                Pov = ovmsk[c & 1];
                Pb = *(const u64*)&clist[c & 1][(wv - 1) * 8];
                const u64* rowbase = RM + (size_t)c * 64 * NW;
                #pragma unroll
                for (int s = 0; s < 8; ++s) {
                    H0[s] = 0; H1[s] = 0;
                    int r = (wv - 1) * 8 + s;
                    if (r < (int)Pnc) {
                        const u64* rp = rowbase + (size_t)((Pb >> (8 * s)) & 0xffu) * NW;
                        H0[s] = rp[lane];
                        H1[s] = rp[64 + lane];
                    }
                }
            } else { Pnc = 0; Pov = 0; }
        }
        barrier_nodrain();
    }
    __syncthreads();

    // ---------------- fused output tail ----------------
    float wreg[FEAT * 4];
    #pragma unroll
    for (int m = 0; m < FEAT * 4; ++m) wreg[m] = Wm[m];
    float bb0 = bv[0], bb1 = bv[1], bb2 = bv[2], bb3 = bv[3];
    float sw = (float)(*widthp), sh = (float)(*heightp);
    for (int k = 0; k < N_BOXES / 512; ++k) {
        int i = tid + 512 * k;
        u32 r = rank_of[i];
        float keep = (float)((keptw[r >> 6] >> (r & 63)) & 1ull);
        float z0 = bb0, z1 = bb1, z2 = bb2, z3 = bb3;
        #pragma unroll
        for (int m = 0; m < FEAT; ++m) {
            float f = features[i * FEAT + m];
            z0 += f * wreg[m * 4 + 0];
            z1 += f * wreg[m * 4 + 1];
            z2 += f * wreg[m * 4 + 2];
            z3 += f * wreg[m * 4 + 3];
        }
        float t0 = 1.0f / (1.0f + expf(-z0));
        float t1 = 1.0f / (1.0f + expf(-z1));
        float t2 = 1.0f / (1.0f + expf(-z2));
        float t3 = 1.0f / (1.0f + expf(-z3));
        float4 bx = ((const float4*)bboxes)[i];
        float ox = fmaxf(t0 * bx.z + bx.x, 0.0f);
        float oy = fmaxf(t1 * bx.w + bx.y, 0.0f);
        float ow = bx.z * expf(t2);
        float oh = bx.w * expf(t3);
        float4 o;
        o.x = ox * sw * keep;
        o.y = oy * sh * keep;
        o.z = ow * sw * keep;
        o.w = oh * sh * keep;
        ((float4*)out)[i] = o;
    }
}

extern "C" void kernel_launch(void* const* d_in, const int* in_sizes, int n_in,
                              void* d_out, int out_size, void* d_ws, size_t ws_size,
                              hipStream_t stream) {
    const float* bboxes   = (const float*)d_in[0];
    const float* scores   = (const float*)d_in[1];
    const float* features = (const float*)d_in[2];
    const float* Wm       = (const float*)d_in[3];
    const float* bv       = (const float*)d_in[4];
    const int*   widthp   = (const int*)d_in[5];
    const int*   heightp  = (const int*)d_in[6];
    float* out = (float*)d_out;

    char* ws = (char*)d_ws;
    u64* RM      = (u64*)ws;                                        // 8 MiB
    u64* TRb     = (u64*)(ws + (size_t)N_BOXES * NW * sizeof(u64)); // 128 KiB
    float* x1s   = (float*)((char*)TRb + (size_t)2 * N_BOXES * sizeof(u64));
    float* y1s   = x1s + N_BOXES;
    float* x2s   = y1s + N_BOXES;
    float* y2s   = x2s + N_BOXES;
    u32* rank_of = (u32*)(y2s + N_BOXES);

    rank_scatter_kernel<<<N_BOXES / 32, 256, 0, stream>>>(bboxes, scores,
                                                          x1s, y1s, x2s, y2s, rank_of);
    mask_kernel<<<dim3(NW / CJG, NW), 256, 0, stream>>>(x1s, y1s, x2s, y2s, RM, TRb);
    nms_reduce_fused<<<1, 512, 0, stream>>>(RM, TRb, rank_of, bboxes, features,
                                            Wm, bv, widthp, heightp, out);
}